// Round 3
// baseline (30893.640 us; speedup 1.0000x reference)
//
#include <hip/hip_runtime.h>
#include <stdint.h>

#define DEV static __device__ __forceinline__

typedef float f32x4 __attribute__((ext_vector_type(4)));
typedef unsigned int u32x4 __attribute__((ext_vector_type(4)));
typedef short s16x8 __attribute__((ext_vector_type(8)));   // 8 bf16 in 4 VGPRs

// round-to-nearest-even f32 -> bf16
DEV unsigned short f2bf(float f) {
    union { float f; unsigned int u; } v; v.f = f;
    unsigned int u = v.u;
    return (unsigned short)((u + 0x7FFFu + ((u >> 16) & 1u)) >> 16);
}

DEV float sigm(float x) { return __fdividef(1.0f, 1.0f + __expf(-x)); }
DEV float tanh_(float x) { return 1.0f - __fdividef(2.0f, __expf(2.0f * x) + 1.0f); }

// D = A*B + C, 16x16x32 bf16 — compiler intrinsic (hazard NOPs + scheduling handled)
DEV f32x4 mfma_bf16(s16x8 a, s16x8 b, f32x4 c) {
    return __builtin_amdgcn_mfma_f32_16x16x32_bf16(a, b, c, 0, 0, 0);
}

// ---------------- packing pre-passes ----------------

// W_hh [1024(n=gate*256+j)][256(k)] -> Wq [256(k)][1024 (j*4+gate)]
__global__ __launch_bounds__(256) void pack_whh(const float* __restrict__ src, float* __restrict__ dst) {
    int o = blockIdx.x * 256 + threadIdx.x;      // 262144
    int k = o >> 10, ci = o & 1023;
    int j = ci >> 2, sg = ci & 3;
    dst[o] = src[(sg * 256 + j) * 256 + k];
}
// W_ih_l0 [1024][16] -> [16][1024 quad-interleaved]
__global__ __launch_bounds__(256) void pack_wih0(const float* __restrict__ src, float* __restrict__ dst) {
    int o = blockIdx.x * 256 + threadIdx.x;      // 16384
    int k = o >> 10, ci = o & 1023;
    int j = ci >> 2, sg = ci & 3;
    dst[o] = src[(sg * 256 + j) * 16 + k];
}
// bias [1024] -> quad-interleaved [j*4+gate]
__global__ __launch_bounds__(256) void pack_bias(const float* __restrict__ src, float* __restrict__ dst) {
    int o = blockIdx.x * 256 + threadIdx.x;      // 1024
    int j = o >> 2, sg = o & 3;
    dst[o] = src[sg * 256 + j];
}
__global__ __launch_bounds__(256) void cvt_bf16(const float* __restrict__ src, unsigned short* __restrict__ dst, int n) {
    int o = blockIdx.x * 256 + threadIdx.x;
    if (o < n) dst[o] = f2bf(src[o]);
}
// fc_w [64][512] -> [512][64]
__global__ __launch_bounds__(256) void transpose_fcw(const float* __restrict__ src, float* __restrict__ dst) {
    int o = blockIdx.x * 256 + threadIdx.x;      // 32768
    int j = o >> 6, l = o & 63;
    dst[o] = src[l * 512 + j];
}

// ---------------- layer 0 step (both directions in one launch) ----------------
// grid = 2<<sub_bits; WG owns 64 batch rows x 16 hidden cols (quad-gate strips).
// h stored transposed [dir][k(256)][b(Bc)], ping-pong hR -> hW.
__global__ __launch_bounds__(256) void l0_step(
    int s, int b0, int Bc, int sub_bits, const float* __restrict__ x,
    const float* __restrict__ WqF, const float* __restrict__ WqB,
    const float* __restrict__ WiqF, const float* __restrict__ WiqB,
    const float* __restrict__ bqF, const float* __restrict__ bqB,
    const float* __restrict__ hR, float* __restrict__ hW,
    float* __restrict__ cst, unsigned short* __restrict__ out0)
{
    __shared__ float h_s[256 * 64];   // [k][r] 64KB
    int tid = threadIdx.x;
    int wg = blockIdx.x;
    int dir = wg >> sub_bits;
    int sub = wg & ((1 << sub_bits) - 1);
    int r0 = (sub >> 4) * 64;
    int j0 = (sub & 15) * 16;
    int t = dir ? (511 - s) : s;
    const float* Wq  = dir ? WqB  : WqF;
    const float* Wiq = dir ? WiqB : WiqF;
    const float* bq  = dir ? bqB  : bqF;
    const float* hsrc = hR + dir * (256 * Bc) + r0;

    #pragma unroll
    for (int i = 0; i < 16; ++i) {
        int idx = i * 256 + tid;
        int k = idx >> 4;
        int rq = (idx & 15) * 4;
        *(float4*)(h_s + k * 64 + rq) = *(const float4*)(hsrc + k * Bc + rq);
    }

    int tx = tid & 15, ty = tid >> 4;

    float xr[4][16];
    #pragma unroll
    for (int i = 0; i < 4; ++i) {
        const float* xp = x + ((size_t)(b0 + r0 + ty * 4 + i) * 512 + t) * 16;
        #pragma unroll
        for (int q = 0; q < 4; ++q) {
            float4 v = *(const float4*)(xp + q * 4);
            xr[i][q * 4 + 0] = v.x; xr[i][q * 4 + 1] = v.y;
            xr[i][q * 4 + 2] = v.z; xr[i][q * 4 + 3] = v.w;
        }
    }
    __syncthreads();

    float g[4][4];   // [row i][gate]
    float4 b4 = *(const float4*)(bq + (j0 + tx) * 4);
    #pragma unroll
    for (int i = 0; i < 4; ++i) { g[i][0] = b4.x; g[i][1] = b4.y; g[i][2] = b4.z; g[i][3] = b4.w; }

    #pragma unroll
    for (int ii = 0; ii < 16; ++ii) {
        float4 w4 = *(const float4*)(Wiq + ii * 1024 + (j0 + tx) * 4);
        #pragma unroll
        for (int i = 0; i < 4; ++i) {
            float a = xr[i][ii];
            g[i][0] += a * w4.x; g[i][1] += a * w4.y; g[i][2] += a * w4.z; g[i][3] += a * w4.w;
        }
    }

    const float* wp = Wq + (j0 + tx) * 4;
    const float* hp = h_s + ty * 4;
    #pragma unroll 8
    for (int k = 0; k < 256; ++k) {
        float4 w4 = *(const float4*)(wp + k * 1024);
        float4 a4 = *(const float4*)(hp + k * 64);
        g[0][0] += a4.x * w4.x; g[0][1] += a4.x * w4.y; g[0][2] += a4.x * w4.z; g[0][3] += a4.x * w4.w;
        g[1][0] += a4.y * w4.x; g[1][1] += a4.y * w4.y; g[1][2] += a4.y * w4.z; g[1][3] += a4.y * w4.w;
        g[2][0] += a4.z * w4.x; g[2][1] += a4.z * w4.y; g[2][2] += a4.z * w4.z; g[2][3] += a4.z * w4.w;
        g[3][0] += a4.w * w4.x; g[3][1] += a4.w * w4.y; g[3][2] += a4.w * w4.z; g[3][3] += a4.w * w4.w;
    }

    float hv[4];
    #pragma unroll
    for (int i = 0; i < 4; ++i) {
        int r = r0 + ty * 4 + i;
        float si = sigm(g[i][0]);
        float sf = sigm(g[i][1]);
        float tg = tanh_(g[i][2]);
        float so = sigm(g[i][3]);
        float* cp = cst + dir * (Bc * 256) + r * 256 + j0 + tx;
        float cn = sf * (*cp) + si * tg;
        *cp = cn;
        float hh = so * tanh_(cn);
        hv[i] = hh;
        out0[((size_t)t * Bc + r) * 512 + (dir << 8) + j0 + tx] = f2bf(hh);
    }
    float4 hq = { hv[0], hv[1], hv[2], hv[3] };
    *(float4*)(hW + dir * (256 * Bc) + (j0 + tx) * Bc + r0 + ty * 4) = hq;
}

// ---------------- layer 1 step ----------------
__global__ __launch_bounds__(256) void l1_step(
    int s, int Bc, int sub_bits,
    const float* __restrict__ G1f, const float* __restrict__ G1b,
    const float* __restrict__ WqF, const float* __restrict__ WqB,
    const float* __restrict__ bqF, const float* __restrict__ bqB,
    const float* __restrict__ hR, float* __restrict__ hW, float* __restrict__ cst)
{
    __shared__ float h_s[256 * 64];
    int tid = threadIdx.x;
    int wg = blockIdx.x;
    int dir = wg >> sub_bits;
    int sub = wg & ((1 << sub_bits) - 1);
    int r0 = (sub >> 4) * 64;
    int j0 = (sub & 15) * 16;
    const float* Wq = dir ? WqB : WqF;
    const float* bq = dir ? bqB : bqF;
    const float* hsrc = hR + dir * (256 * Bc) + r0;
    int slot = dir ? (7 - (s & 7)) : (s & 7);

    #pragma unroll
    for (int i = 0; i < 16; ++i) {
        int idx = i * 256 + tid;
        int k = idx >> 4;
        int rq = (idx & 15) * 4;
        *(float4*)(h_s + k * 64 + rq) = *(const float4*)(hsrc + k * Bc + rq);
    }

    int tx = tid & 15, ty = tid >> 4;
    __syncthreads();

    float g[4][4];
    float4 b4 = *(const float4*)(bq + (j0 + tx) * 4);
    const float* Gp = (dir ? G1b : G1f) + (size_t)(slot * Bc + r0 + ty * 4) * 1024 + j0 + tx;
    #pragma unroll
    for (int i = 0; i < 4; ++i) {
        const float* gp = Gp + (size_t)i * 1024;
        g[i][0] = b4.x + gp[0];
        g[i][1] = b4.y + gp[256];
        g[i][2] = b4.z + gp[512];
        g[i][3] = b4.w + gp[768];
    }

    const float* wp = Wq + (j0 + tx) * 4;
    const float* hp = h_s + ty * 4;
    #pragma unroll 8
    for (int k = 0; k < 256; ++k) {
        float4 w4 = *(const float4*)(wp + k * 1024);
        float4 a4 = *(const float4*)(hp + k * 64);
        g[0][0] += a4.x * w4.x; g[0][1] += a4.x * w4.y; g[0][2] += a4.x * w4.z; g[0][3] += a4.x * w4.w;
        g[1][0] += a4.y * w4.x; g[1][1] += a4.y * w4.y; g[1][2] += a4.y * w4.z; g[1][3] += a4.y * w4.w;
        g[2][0] += a4.z * w4.x; g[2][1] += a4.z * w4.y; g[2][2] += a4.z * w4.z; g[2][3] += a4.z * w4.w;
        g[3][0] += a4.w * w4.x; g[3][1] += a4.w * w4.y; g[3][2] += a4.w * w4.z; g[3][3] += a4.w * w4.w;
    }

    float hv[4];
    #pragma unroll
    for (int i = 0; i < 4; ++i) {
        int r = r0 + ty * 4 + i;
        float si = sigm(g[i][0]);
        float sf = sigm(g[i][1]);
        float tg = tanh_(g[i][2]);
        float so = sigm(g[i][3]);
        float* cp = cst + dir * (Bc * 256) + r * 256 + j0 + tx;
        float cn = sf * (*cp) + si * tg;
        *cp = cn;
        hv[i] = so * tanh_(cn);
    }
    float4 hq = { hv[0], hv[1], hv[2], hv[3] };
    *(float4*)(hW + dir * (256 * Bc) + (j0 + tx) * Bc + r0 + ty * 4) = hq;
}

// ---------------- layer-1 input GEMM: G1 = out0_chunk @ W_ih_l1^T (bf16 MFMA) ----------------
// A [M=8*Bc rows=(t_local*Bc+b)][512] bf16, W [1024][512] bf16, G [M][1024] f32
// grid = 2 << (3+mt_bits); 128x128 tile, 4 waves of 64x64.
__global__ __launch_bounds__(256) void g1_gemm(
    int mt_bits,
    const unsigned short* __restrict__ Af, const unsigned short* __restrict__ Ab,
    const unsigned short* __restrict__ Wf, const unsigned short* __restrict__ Wb,
    float* __restrict__ Gf, float* __restrict__ Gb)
{
    __shared__ unsigned short As[128 * 40];
    __shared__ unsigned short Bs[128 * 40];
    int gid = blockIdx.x;
    int dir = gid >> (3 + mt_bits);
    int rem = gid & ((1 << (3 + mt_bits)) - 1);
    int n0 = (rem >> mt_bits) << 7;
    int m0 = (rem & ((1 << mt_bits) - 1)) << 7;
    const unsigned short* A = dir ? Ab : Af;
    const unsigned short* W = dir ? Wb : Wf;
    float* G = dir ? Gb : Gf;
    int tid = threadIdx.x;
    int lane = tid & 63, wave = tid >> 6;
    int wm = (wave >> 1) * 64, wn = (wave & 1) * 64;
    int l15 = lane & 15, lq = lane >> 4;

    f32x4 acc[4][4];
    f32x4 z = { 0.f, 0.f, 0.f, 0.f };
    #pragma unroll
    for (int i = 0; i < 4; ++i)
        #pragma unroll
        for (int j = 0; j < 4; ++j) acc[i][j] = z;

    for (int k0 = 0; k0 < 512; k0 += 32) {
        #pragma unroll
        for (int h = 0; h < 2; ++h) {
            int sseg = h * 256 + tid;          // 512 segments of 16B per tile
            int row = sseg >> 2, q = sseg & 3;
            *(u32x4*)(As + row * 40 + q * 8) = *(const u32x4*)(A + (size_t)(m0 + row) * 512 + k0 + q * 8);
            *(u32x4*)(Bs + row * 40 + q * 8) = *(const u32x4*)(W + (size_t)(n0 + row) * 512 + k0 + q * 8);
        }
        __syncthreads();
        s16x8 af[4], bf[4];
        #pragma unroll
        for (int i = 0; i < 4; ++i) {
            af[i] = *(const s16x8*)(As + (wm + i * 16 + l15) * 40 + lq * 8);
            bf[i] = *(const s16x8*)(Bs + (wn + i * 16 + l15) * 40 + lq * 8);
        }
        #pragma unroll
        for (int i = 0; i < 4; ++i)
            #pragma unroll
            for (int j = 0; j < 4; ++j)
                acc[i][j] = mfma_bf16(af[i], bf[j], acc[i][j]);
        __syncthreads();
    }
    #pragma unroll
    for (int i = 0; i < 4; ++i)
        #pragma unroll
        for (int j = 0; j < 4; ++j)
            #pragma unroll
            for (int e = 0; e < 4; ++e) {
                int row = m0 + wm + i * 16 + lq * 4 + e;
                int col = n0 + wn + j * 16 + l15;
                G[(size_t)row * 1024 + col] = acc[i][j][e];
            }
}

// ---------------- final FC ----------------
__global__ __launch_bounds__(64) void fc_kernel(
    const float* __restrict__ hT, const float* __restrict__ fcwT,
    const float* __restrict__ fcb, float* __restrict__ out, int b0, int Bc)
{
    __shared__ float hc[512];
    int b = blockIdx.x, l = threadIdx.x;
    #pragma unroll
    for (int q = 0; q < 4; ++q) {
        int j = q * 64 + l;
        hc[j]       = hT[(size_t)j * Bc + b];
        hc[256 + j] = hT[(size_t)256 * Bc + (size_t)j * Bc + b];
    }
    __syncthreads();
    float acc = fcb[l];
    for (int j = 0; j < 512; ++j) acc += hc[j] * fcwT[j * 64 + l];
    out[(b0 + b) * 64 + l] = acc;
}

// ---------------- host ----------------
extern "C" void kernel_launch(void* const* d_in, const int* in_sizes, int n_in,
                              void* d_out, int out_size, void* d_ws, size_t ws_size,
                              hipStream_t stream)
{
    const float* x     = (const float*)d_in[0];
    const float* wih0f = (const float*)d_in[1];
    const float* whh0f = (const float*)d_in[2];
    const float* b0f   = (const float*)d_in[3];
    const float* wih0b = (const float*)d_in[4];
    const float* whh0b = (const float*)d_in[5];
    const float* b0b   = (const float*)d_in[6];
    const float* wih1f = (const float*)d_in[7];
    const float* whh1f = (const float*)d_in[8];
    const float* b1f   = (const float*)d_in[9];
    const float* wih1b = (const float*)d_in[10];
    const float* whh1b = (const float*)d_in[11];
    const float* b1b   = (const float*)d_in[12];
    const float* fcw   = (const float*)d_in[13];
    const float* fcb   = (const float*)d_in[14];
    float* out = (float*)d_out;
    (void)in_sizes; (void)n_in; (void)out_size;

    // ---- pick batch-chunk size Bc to fit ws_size ----
    // per-batch-row bytes: out0 512*512*2 + G 2*8*1024*4 + hbuf 2*2*256*4 + cbuf 2*256*4
    const size_t per_row = 524288 + 65536 + 8192 + 2048;   // 600064
    const size_t fixed   = 4u*1048576 + 2u*65536 + 4u*4096 + 2u*1048576 + 131072 + 65536;
    int Bc = 512;
    while (Bc > 64 && fixed + per_row * (size_t)Bc > ws_size) Bc >>= 1;
    const int nb = 512 / Bc;
    const int sub_bits = 4 + (31 - __builtin_clz((unsigned)(Bc >> 6)));  // log2(Bc/64*16)
    const int mt_bits  = (31 - __builtin_clz((unsigned)Bc)) - 4;         // log2(8*Bc/128)
    const int gemm_grid = 2 << (3 + mt_bits);
    const int step_grid = 2 << sub_bits;

    char* p = (char*)d_ws;
    auto alloc = [&](size_t bytes) -> void* {
        void* r = (void*)p;
        p += (bytes + 255) & ~(size_t)255;
        return r;
    };
    float* Wq0f = (float*)alloc(256 * 1024 * 4);
    float* Wq0b = (float*)alloc(256 * 1024 * 4);
    float* Wq1f = (float*)alloc(256 * 1024 * 4);
    float* Wq1b = (float*)alloc(256 * 1024 * 4);
    float* Wiq0f = (float*)alloc(16 * 1024 * 4);
    float* Wiq0b = (float*)alloc(16 * 1024 * 4);
    float* bq0f = (float*)alloc(1024 * 4);
    float* bq0b = (float*)alloc(1024 * 4);
    float* bq1f = (float*)alloc(1024 * 4);
    float* bq1b = (float*)alloc(1024 * 4);
    unsigned short* W1bf_f = (unsigned short*)alloc(1024 * 512 * 2);
    unsigned short* W1bf_b = (unsigned short*)alloc(1024 * 512 * 2);
    float* fcwT = (float*)alloc(512 * 64 * 4);
    float* hbuf = (float*)alloc((size_t)2 * 2 * 256 * Bc * 4);   // [pingpong][dir][k][b]
    float* cbuf = (float*)alloc((size_t)2 * Bc * 256 * 4);       // [dir][b][j]
    unsigned short* out0 = (unsigned short*)alloc((size_t)512 * Bc * 512 * 2);  // [t][b][2H] bf16
    float* G1f = (float*)alloc((size_t)8 * Bc * 1024 * 4);       // chunk [8][Bc][1024]
    float* G1b = (float*)alloc((size_t)8 * Bc * 1024 * 4);

    pack_whh<<<1024, 256, 0, stream>>>(whh0f, Wq0f);
    pack_whh<<<1024, 256, 0, stream>>>(whh0b, Wq0b);
    pack_whh<<<1024, 256, 0, stream>>>(whh1f, Wq1f);
    pack_whh<<<1024, 256, 0, stream>>>(whh1b, Wq1b);
    pack_wih0<<<64, 256, 0, stream>>>(wih0f, Wiq0f);
    pack_wih0<<<64, 256, 0, stream>>>(wih0b, Wiq0b);
    pack_bias<<<4, 256, 0, stream>>>(b0f, bq0f);
    pack_bias<<<4, 256, 0, stream>>>(b0b, bq0b);
    pack_bias<<<4, 256, 0, stream>>>(b1f, bq1f);
    pack_bias<<<4, 256, 0, stream>>>(b1b, bq1b);
    cvt_bf16<<<2048, 256, 0, stream>>>(wih1f, W1bf_f, 1024 * 512);
    cvt_bf16<<<2048, 256, 0, stream>>>(wih1b, W1bf_b, 1024 * 512);
    transpose_fcw<<<128, 256, 0, stream>>>(fcw, fcwT);

    for (int bchunk = 0; bchunk < nb; ++bchunk) {
        int b0 = bchunk * Bc;

        // ---- layer 0 ----
        hipMemsetAsync(hbuf, 0, (size_t)2 * 2 * 256 * Bc * 4, stream);
        hipMemsetAsync(cbuf, 0, (size_t)2 * Bc * 256 * 4, stream);
        for (int s = 0; s < 512; ++s) {
            const float* hRp = hbuf + (size_t)(s & 1) * (2 * 256 * Bc);
            float* hWp = hbuf + (size_t)((s + 1) & 1) * (2 * 256 * Bc);
            l0_step<<<step_grid, 256, 0, stream>>>(s, b0, Bc, sub_bits, x,
                                                   Wq0f, Wq0b, Wiq0f, Wiq0b,
                                                   bq0f, bq0b, hRp, hWp, cbuf, out0);
        }

        // ---- layer 1, 8-step chunks: input GEMM + steps ----
        hipMemsetAsync(hbuf, 0, (size_t)2 * 2 * 256 * Bc * 4, stream);
        hipMemsetAsync(cbuf, 0, (size_t)2 * Bc * 256 * 4, stream);
        for (int c = 0; c < 64; ++c) {
            const unsigned short* Afp = out0 + (size_t)(c * 8) * Bc * 512;         // fwd t in [8c, 8c+8)
            const unsigned short* Abp = out0 + (size_t)(504 - 8 * c) * Bc * 512;   // bwd t in [504-8c, 512-8c)
            g1_gemm<<<gemm_grid, 256, 0, stream>>>(mt_bits, Afp, Abp, W1bf_f, W1bf_b, G1f, G1b);
            for (int i = 0; i < 8; ++i) {
                int s = c * 8 + i;
                const float* hRp = hbuf + (size_t)(s & 1) * (2 * 256 * Bc);
                float* hWp = hbuf + (size_t)((s + 1) & 1) * (2 * 256 * Bc);
                l1_step<<<step_grid, 256, 0, stream>>>(s, Bc, sub_bits, G1f, G1b,
                                                       Wq1f, Wq1b, bq1f, bq1b, hRp, hWp, cbuf);
            }
        }

        fc_kernel<<<Bc, 64, 0, stream>>>(hbuf, fcwT, fcb, out, b0, Bc);
    }
}